// Round 7
// baseline (162.629 us; speedup 1.0000x reference)
//
#include <hip/hip_runtime.h>

// AntModel: counts flow through 3 routing layers.
//   dest_k[s] = argmax_j W_k[s, j]   (first max index, ties broken low)
//   out[b, dest3[dest2[dest1[s]]]] += x[b, s]; relu is identity on counts.
//
// Round-7 experiment: round-4 block-burst argmax (each step = one contiguous
//   16KB unit read by a 1024-thread block, rows contiguous across blocks,
//   1-deep prefetch) with NON-TEMPORAL loads. Round 6 proved nt is causal
//   (argmax 56 -> <40us: L3-bypass avoids the mixed hit/miss regime created
//   by the harness's 268MB/iter reset fill). This round tests whether request
//   dispersion matters in the pure-HBM nt regime (it was null in the
//   L3-mediated regime, round 4): block-burst keeps the chip's instantaneous
//   request window dense/contiguous for the memory controllers.
// Kernel 2: compose routing tables (tiny).
// Kernel 3: per-batch LDS histogram scatter, 1024 threads.

#define N_IN   4096
#define N_MID  4096
#define N_OUT  1024
#define BATCH  256

typedef float f4 __attribute__((ext_vector_type(4)));

// Monotone map float->u32 (total order, matches float compare for non-NaN),
// then key = (u << 32) | ~idx : max(key) == (max value, min index).
__device__ __forceinline__ unsigned long long pack_key(float v, int idx) {
    unsigned b = __float_as_uint(v);
    unsigned u = (b & 0x80000000u) ? ~b : (b | 0x80000000u);
    return ((unsigned long long)u << 32) | (unsigned)(~idx);
}

// Units of 16KB: W1 rows -> blocks 0..511 (8 rows each), W2 -> 512..1023,
// W3 (4 rows per 16KB unit, 1024 units) -> blocks 1024..1151. Grid = 1152.
__global__ __launch_bounds__(1024, 8) void argmax_all_kernel(
    const float* __restrict__ W1, const float* __restrict__ W2,
    const float* __restrict__ W3, int* __restrict__ dest1,
    int* __restrict__ dest2, int* __restrict__ dest3) {
    __shared__ unsigned long long partials[8][16];
    const int tid  = threadIdx.x;
    const int w    = tid >> 6;    // wave 0..15
    const int lane = tid & 63;
    const int blk  = blockIdx.x;

    const float* Wm;
    int kLoc;
    if (blk < 512)       { Wm = W1; kLoc = blk; }
    else if (blk < 1024) { Wm = W2; kLoc = blk - 512; }
    else                 { Wm = W3; kLoc = blk - 1024; }   // 0..127
    const bool isW3 = (blk >= 1024);

    const f4* __restrict__ p = reinterpret_cast<const f4*>(Wm);
    // unit j covers float4s [(8*kLoc+j)<<10, +1024); thread reads slot tid.
    const size_t base = ((size_t)(8 * kLoc) << 10) + tid;
    // column of this thread's float4 within its row
    const int c = (isW3 ? (tid & 255) : tid) * 4;

    f4 cur = __builtin_nontemporal_load(p + base);
    #pragma unroll
    for (int j = 0; j < 8; ++j) {
        f4 nxt = cur;
        if (j < 7) nxt = __builtin_nontemporal_load(p + base + ((size_t)(j + 1) << 10));
        __builtin_amdgcn_sched_barrier(0);  // keep prefetch above the reduce

        float bv = cur.x; int bi = c;
        if (cur.y > bv) { bv = cur.y; bi = c + 1; }   // strict > keeps first
        if (cur.z > bv) { bv = cur.z; bi = c + 2; }
        if (cur.w > bv) { bv = cur.w; bi = c + 3; }
        unsigned long long key = pack_key(bv, bi);
        #pragma unroll
        for (int off = 1; off < 64; off <<= 1) {
            unsigned long long o = __shfl_xor(key, off, 64);
            if (o > key) key = o;
        }
        if (lane == 0) partials[j][w] = key;
        cur = nxt;
    }
    __syncthreads();

    // Final reduce: 2 waves, each 16-lane group handles one unit's 16 partials.
    if (tid < 128) {
        const int j = tid >> 4, slot = tid & 15;
        unsigned long long key = partials[j][slot];
        if (!isW3) {
            #pragma unroll
            for (int off = 1; off < 16; off <<= 1) {
                unsigned long long o = __shfl_xor(key, off, 64);
                if (o > key) key = o;
            }
            if (slot == 0) {
                int idx = (int)~(unsigned)(key & 0xFFFFFFFFull);
                int row = 8 * kLoc + j;
                if (blk < 512) dest1[row] = idx; else dest2[row] = idx;
            }
        } else {
            // unit = 4 rows; 16 wave-partials = 4 consecutive per row.
            // off 1,2 only touch slot bits 0-1, staying within each row's 4.
            #pragma unroll
            for (int off = 1; off < 4; off <<= 1) {
                unsigned long long o = __shfl_xor(key, off, 64);
                if (o > key) key = o;
            }
            if ((slot & 3) == 0) {
                int idx = (int)~(unsigned)(key & 0xFFFFFFFFull);
                int g = 8 * kLoc + j;                 // W3 unit 0..1023
                dest3[4 * g + (slot >> 2)] = idx;     // rows 0..4095
            }
        }
    }
}

__global__ __launch_bounds__(256) void compose_kernel(
    const int* __restrict__ dest1, const int* __restrict__ dest2,
    const int* __restrict__ dest3, int* __restrict__ fdest) {
    const int s = blockIdx.x * blockDim.x + threadIdx.x;
    if (s < N_IN) fdest[s] = dest3[dest2[dest1[s]]];
}

__global__ __launch_bounds__(1024) void scatter_kernel(
    const int* __restrict__ x, const int* __restrict__ fdest,
    float* __restrict__ out) {
    __shared__ int cnt[N_OUT];
    const int b   = blockIdx.x;
    const int tid = threadIdx.x;
    cnt[tid] = 0;   // 1024 threads cover N_OUT exactly
    __syncthreads();
    const int4 v = reinterpret_cast<const int4*>(x + (size_t)b * N_IN)[tid];
    const int4 d = reinterpret_cast<const int4*>(fdest)[tid];
    atomicAdd(&cnt[d.x], v.x);
    atomicAdd(&cnt[d.y], v.y);
    atomicAdd(&cnt[d.z], v.z);
    atomicAdd(&cnt[d.w], v.w);
    __syncthreads();
    out[(size_t)b * N_OUT + tid] = (float)cnt[tid];
}

extern "C" void kernel_launch(void* const* d_in, const int* in_sizes, int n_in,
                              void* d_out, int out_size, void* d_ws, size_t ws_size,
                              hipStream_t stream) {
    const int*   x  = (const int*)d_in[0];
    const float* W1 = (const float*)d_in[1];
    const float* W2 = (const float*)d_in[2];
    const float* W3 = (const float*)d_in[3];
    float* out = (float*)d_out;

    int* ws    = (int*)d_ws;
    int* dest1 = ws;               // [4096]
    int* dest2 = ws + N_IN;        // [4096]
    int* dest3 = ws + 2 * N_IN;    // [4096] rows of W3
    int* fdest = ws + 3 * N_IN;    // [4096]

    // 9216 contiguous 16KB units / 8 per block = 1152 blocks.
    argmax_all_kernel<<<1152, 1024, 0, stream>>>(W1, W2, W3,
                                                 dest1, dest2, dest3);
    compose_kernel<<<N_IN / 256, 256, 0, stream>>>(dest1, dest2, dest3, fdest);
    scatter_kernel<<<BATCH, 1024, 0, stream>>>(x, fdest, out);
}

// Round 9
// 158.632 us; speedup vs baseline: 1.0252x; 1.0252x over previous
//
#include <hip/hip_runtime.h>

// AntModel: counts flow through 3 routing layers.
//   dest_k[s] = argmax_j W_k[s, j]   (first max index, ties broken low)
//   out[b, dest3[dest2[dest1[s]]]] += x[b, s]; relu is identity on counts.
//
// Round-9: round-6 verified structure (best: 158.9us), dispatches cut 3 -> 2.
//   Kernel 1: wave-per-row argmax with 8-deep NON-TEMPORAL load batches.
//     nt bypasses L3 allocation — the harness's 2^28-byte poison fill churns
//     the entire 256MiB L3 every iteration, so plain loads hit a pathological
//     mixed L3-hit/HBM-miss regime (56us); nt streams pure-HBM (<40us,
//     round-6's -13us win). Access-pattern variants (MLP depth, block-burst)
//     are all null (rounds 1,2,4,7): the nt read service rate is the floor.
//   Kernel 2: scatter with compose fused — each block recomputes the 4096-
//     entry routing composition into LDS from the three 16KB tables (L2-hot,
//     ~redundant but ~free), removing the compose kernel + one dispatch
//     boundary + the global fdest round-trip.
//   NOTE: cooperative full fusion is NOT possible here — hipLaunchCooperative-
//   Kernel silently fails under the harness's graph capture (round-8 failure:
//   zero output, absmax == max|ref|).

#define N_IN   4096
#define N_MID  4096
#define N_OUT  1024
#define BATCH  256

typedef float f4 __attribute__((ext_vector_type(4)));

__device__ __forceinline__ void upd(float v, int idx, float& bv, int& bi) {
    // strictly-greater keeps the FIRST occurrence of the max (jnp.argmax semantics)
    if (v > bv || (v == bv && idx < bi)) { bv = v; bi = idx; }
}

template <int NCOLS>
__device__ __forceinline__ void row_argmax(const float* __restrict__ W, int row,
                                           int* __restrict__ dest) {
    const int lane = threadIdx.x & 63;
    const f4* __restrict__ p =
        reinterpret_cast<const f4*>(W + (size_t)row * NCOLS);
    float bv = -__builtin_huge_valf();
    int bi = 0;
    constexpr int ITERS = NCOLS / 256;              // 16 (4096 cols) or 4 (1024)
    constexpr int BAT   = (ITERS >= 8) ? 8 : ITERS; // loads kept in flight
    #pragma unroll
    for (int t0 = 0; t0 < ITERS; t0 += BAT) {
        f4 v[BAT];
        #pragma unroll
        for (int u = 0; u < BAT; ++u)
            v[u] = __builtin_nontemporal_load(p + (size_t)(t0 + u) * 64 + lane);
        __builtin_amdgcn_sched_barrier(0);  // pin the load batch above the consume
        #pragma unroll
        for (int u = 0; u < BAT; ++u) {
            int c = (t0 + u) * 256 + lane * 4;
            upd(v[u].x, c + 0, bv, bi);
            upd(v[u].y, c + 1, bv, bi);
            upd(v[u].z, c + 2, bv, bi);
            upd(v[u].w, c + 3, bv, bi);
        }
    }
    // wave-64 butterfly reduce; (value desc, index asc) is a total order so
    // xor-reduce is associative/commutative-safe.
    #pragma unroll
    for (int off = 1; off < 64; off <<= 1) {
        float ov = __shfl_xor(bv, off, 64);
        int   oi = __shfl_xor(bi, off, 64);
        if (ov > bv || (ov == bv && oi < bi)) { bv = ov; bi = oi; }
    }
    if (lane == 0) dest[row] = bi;
}

__global__ __launch_bounds__(256) void argmax_all_kernel(
    const float* __restrict__ W1, const float* __restrict__ W2,
    const float* __restrict__ W3, int* __restrict__ dest1,
    int* __restrict__ dest2, int* __restrict__ dest3) {
    const int wave = (blockIdx.x * blockDim.x + threadIdx.x) >> 6;
    if (wave < N_IN) {
        row_argmax<N_MID>(W1, wave, dest1);
    } else if (wave < N_IN + N_MID) {
        row_argmax<N_MID>(W2, wave - N_IN, dest2);
    } else {
        row_argmax<N_OUT>(W3, wave - (N_IN + N_MID), dest3);
    }
}

__global__ __launch_bounds__(1024) void scatter_fused_kernel(
    const int* __restrict__ x, const int* __restrict__ dest1,
    const int* __restrict__ dest2, const int* __restrict__ dest3,
    float* __restrict__ out) {
    __shared__ int fd[N_IN];     // 16KB: composed routing, block-private
    __shared__ int cnt[N_OUT];   // 4KB
    const int b   = blockIdx.x;
    const int tid = threadIdx.x;

    cnt[tid] = 0;   // 1024 threads cover N_OUT exactly
    // Compose: 4 sources/thread, stride-1024 so dest1 reads coalesce; the
    // chained dest2/dest3 gathers hit the L2-hot 16KB tables.
    #pragma unroll
    for (int k = 0; k < N_IN / 1024; ++k) {
        int s = tid + k * 1024;
        fd[s] = dest3[dest2[dest1[s]]];
    }
    __syncthreads();

    // 4096 sources / 1024 threads: one int4 of counts, one LDS int4 of dests.
    const int4 v = reinterpret_cast<const int4*>(x + (size_t)b * N_IN)[tid];
    const int4 d = *reinterpret_cast<const int4*>(&fd[tid * 4]);
    atomicAdd(&cnt[d.x], v.x);
    atomicAdd(&cnt[d.y], v.y);
    atomicAdd(&cnt[d.z], v.z);
    atomicAdd(&cnt[d.w], v.w);
    __syncthreads();
    out[(size_t)b * N_OUT + tid] = (float)cnt[tid];
}

extern "C" void kernel_launch(void* const* d_in, const int* in_sizes, int n_in,
                              void* d_out, int out_size, void* d_ws, size_t ws_size,
                              hipStream_t stream) {
    const int*   x  = (const int*)d_in[0];
    const float* W1 = (const float*)d_in[1];
    const float* W2 = (const float*)d_in[2];
    const float* W3 = (const float*)d_in[3];
    float* out = (float*)d_out;

    int* ws    = (int*)d_ws;
    int* dest1 = ws;               // [4096]
    int* dest2 = ws + N_IN;        // [4096]
    int* dest3 = ws + 2 * N_IN;    // [4096] rows of W3

    // 12288 rows total, 1 wave each, 4 waves per 256-thread block.
    const int total_waves = N_IN + N_MID + N_MID;  // 4096*3
    argmax_all_kernel<<<total_waves / 4, 256, 0, stream>>>(W1, W2, W3,
                                                           dest1, dest2, dest3);
    scatter_fused_kernel<<<BATCH, 1024, 0, stream>>>(x, dest1, dest2, dest3, out);
}